// Round 1
// baseline (319.576 us; speedup 1.0000x reference)
//
#include <hip/hip_runtime.h>
#include <math.h>

// Problem constants (from reference)
constexpr int    N       = 8388608;   // B
constexpr int    THREADS = 256;
constexpr int    BLOCKS  = 2048;
constexpr int    VEC     = 4;
constexpr int    ITERS   = N / (BLOCKS * THREADS * VEC);  // = 4, exact
constexpr int    NSUMS   = 9;
// sum layout: 0:Σs 1:Σm 2:Σl 3:Σs² 4:Σm² 5:Σl² 6:Σsm 7:Σsl 8:Σml

__device__ inline double wave_reduce(double x) {
#pragma unroll
    for (int off = 32; off > 0; off >>= 1)
        x += __shfl_down(x, off, 64);
    return x;
}

__device__ inline void elem_compute(float cq, float pq, float u, int a, float sc, float fq,
                                    float ms, float inv_ms,
                                    float alpha, float beta, float gamma,
                                    float& rs, float& rm, float& rl, float& tot)
{
    rs = cq - pq;
    // stop reward
    float stop_r = (u < 0.3f) ? 0.5f : ((u > 0.7f) ? -0.5f : 0.0f);
    // continue reward
    float cont = (u > 0.5f) ? (0.5f * u) : (-0.5f * (1.0f - u));
    cont -= (sc > 0.8f * ms) ? 0.3f : 0.0f;   // 0.8f*20.0f rounds to exactly 16.0f, matches ref
    float t = sc * inv_ms;                    // |err| vs sc/ms ~1 ulp, far below threshold
    rm = ((a == 0) ? stop_r : cont) - 0.1f * t;
    rl = fq + 0.5f * (1.0f - t);
    tot = alpha * rs + beta * rm + gamma * rl;
}

__global__ __launch_bounds__(THREADS) void reward_main(
    const float* __restrict__ cq, const float* __restrict__ pq,
    const float* __restrict__ un, const int*  __restrict__ ac,
    const float* __restrict__ sc, const float* __restrict__ fq,
    const float* __restrict__ alpha_p, const float* __restrict__ beta_p,
    const float* __restrict__ gamma_p, const int* __restrict__ ms_p,
    float* __restrict__ out, double* __restrict__ partials)
{
    const float alpha = alpha_p[0], beta = beta_p[0], gamma = gamma_p[0];
    const float ms = (float)ms_p[0];
    const float inv_ms = 1.0f / ms;

    const float4* cq4 = (const float4*)cq;
    const float4* pq4 = (const float4*)pq;
    const float4* un4 = (const float4*)un;
    const int4*   ac4 = (const int4*)ac;
    const float4* sc4 = (const float4*)sc;
    const float4* fq4 = (const float4*)fq;

    float* out_tot = out;            // [0, N)
    float* out_s   = out + N + 1;    // r_short
    float* out_m   = out + 2 * N + 1;
    float* out_l   = out + 3 * N + 1;

    double acc[NSUMS];
#pragma unroll
    for (int s = 0; s < NSUMS; ++s) acc[s] = 0.0;

    const int tid = blockIdx.x * THREADS + threadIdx.x;   // 0 .. 524287

#pragma unroll
    for (int it = 0; it < ITERS; ++it) {
        const int idx4 = tid + it * (BLOCKS * THREADS);
        float4 q = cq4[idx4];
        float4 p = pq4[idx4];
        float4 u = un4[idx4];
        int4   a = ac4[idx4];
        float4 s = sc4[idx4];
        float4 f = fq4[idx4];

        float qc[4] = {q.x, q.y, q.z, q.w};
        float pc[4] = {p.x, p.y, p.z, p.w};
        float uc[4] = {u.x, u.y, u.z, u.w};
        int   av[4] = {a.x, a.y, a.z, a.w};
        float sv[4] = {s.x, s.y, s.z, s.w};
        float fv[4] = {f.x, f.y, f.z, f.w};

        float rs[4], rm[4], rl[4], tt[4];
#pragma unroll
        for (int k = 0; k < 4; ++k) {
            elem_compute(qc[k], pc[k], uc[k], av[k], sv[k], fv[k],
                         ms, inv_ms, alpha, beta, gamma,
                         rs[k], rm[k], rl[k], tt[k]);
            double ds = (double)rs[k], dm = (double)rm[k], dl = (double)rl[k];
            acc[0] += ds;      acc[1] += dm;      acc[2] += dl;
            acc[3] += ds * ds; acc[4] += dm * dm; acc[5] += dl * dl;
            acc[6] += ds * dm; acc[7] += ds * dl; acc[8] += dm * dl;
        }

        ((float4*)out_tot)[idx4] = make_float4(tt[0], tt[1], tt[2], tt[3]);
        const int base = idx4 * 4;
#pragma unroll
        for (int k = 0; k < 4; ++k) {
            out_s[base + k] = rs[k];
            out_m[base + k] = rm[k];
            out_l[base + k] = rl[k];
        }
    }

    // block reduction of 9 sums
    __shared__ double red[NSUMS][THREADS / 64];
    const int lane = threadIdx.x & 63;
    const int wave = threadIdx.x >> 6;
#pragma unroll
    for (int s = 0; s < NSUMS; ++s) {
        double w = wave_reduce(acc[s]);
        if (lane == 0) red[s][wave] = w;
    }
    __syncthreads();
    if (threadIdx.x == 0) {
#pragma unroll
        for (int s = 0; s < NSUMS; ++s) {
            double t = 0.0;
#pragma unroll
            for (int w = 0; w < THREADS / 64; ++w) t += red[s][w];
            partials[blockIdx.x * NSUMS + s] = t;
        }
    }
}

__global__ __launch_bounds__(256) void reward_finish(const double* __restrict__ partials,
                                                     float* __restrict__ out)
{
    double loc[NSUMS];
#pragma unroll
    for (int s = 0; s < NSUMS; ++s) loc[s] = 0.0;
    for (int i = threadIdx.x; i < BLOCKS; i += 256) {
#pragma unroll
        for (int s = 0; s < NSUMS; ++s) loc[s] += partials[i * NSUMS + s];
    }
    __shared__ double red[NSUMS][4];
    const int lane = threadIdx.x & 63;
    const int wave = threadIdx.x >> 6;
#pragma unroll
    for (int s = 0; s < NSUMS; ++s) {
        double w = wave_reduce(loc[s]);
        if (lane == 0) red[s][wave] = w;
    }
    __syncthreads();
    if (threadIdx.x == 0) {
        double S[NSUMS];
#pragma unroll
        for (int s = 0; s < NSUMS; ++s)
            S[s] = red[s][0] + red[s][1] + red[s][2] + red[s][3];

        const double n = (double)N;
        double mx = S[0] / n, mm = S[1] / n, ml = S[2] / n;
        double cov_sm = S[6] / n - mx * mm;
        double cov_sl = S[7] / n - mx * ml;
        double cov_ml = S[8] / n - mm * ml;
        double sdS = sqrt((S[3] - n * mx * mx) / (n - 1.0)) + 1e-8;
        double sdM = sqrt((S[4] - n * mm * mm) / (n - 1.0)) + 1e-8;
        double sdL = sqrt((S[5] - n * ml * ml) / (n - 1.0)) + 1e-8;
        double c1 = cov_sm / (sdS * sdM);
        double c2 = cov_sl / (sdS * sdL);
        double c3 = cov_ml / (sdM * sdL);
        out[N] = (float)(c1 * c1 + c2 * c2 + c3 * c3);   // ORTHO_W = 1
    }
}

extern "C" void kernel_launch(void* const* d_in, const int* in_sizes, int n_in,
                              void* d_out, int out_size, void* d_ws, size_t ws_size,
                              hipStream_t stream)
{
    const float* cq   = (const float*)d_in[0];
    const float* pq   = (const float*)d_in[1];
    const float* un   = (const float*)d_in[2];
    const int*   ac   = (const int*)d_in[3];
    const float* sc   = (const float*)d_in[4];
    const float* fq   = (const float*)d_in[5];
    const float* alp  = (const float*)d_in[6];
    const float* bet  = (const float*)d_in[7];
    const float* gam  = (const float*)d_in[8];
    const int*   msp  = (const int*)d_in[9];
    float*  out      = (float*)d_out;
    double* partials = (double*)d_ws;   // 2048 * 9 * 8 B = 144 KiB

    reward_main<<<BLOCKS, THREADS, 0, stream>>>(cq, pq, un, ac, sc, fq,
                                                alp, bet, gam, msp, out, partials);
    reward_finish<<<1, 256, 0, stream>>>(partials, out);
}

// Round 2
// 307.400 us; speedup vs baseline: 1.0396x; 1.0396x over previous
//
#include <hip/hip_runtime.h>
#include <math.h>

// Problem constants (from reference)
constexpr int    N       = 8388608;   // B
constexpr int    THREADS = 256;
constexpr int    BLOCKS  = 2048;
constexpr int    VEC     = 4;
constexpr int    ITERS   = N / (BLOCKS * THREADS * VEC);  // = 4, exact
constexpr int    NSUMS   = 9;
// sum layout: 0:Σs 1:Σm 2:Σl 3:Σs² 4:Σm² 5:Σl² 6:Σsm 7:Σsl 8:Σml

__device__ inline double wave_reduce(double x) {
#pragma unroll
    for (int off = 32; off > 0; off >>= 1)
        x += __shfl_down(x, off, 64);
    return x;
}

__device__ inline void elem_compute(float cq, float pq, float u, int a, float sc, float fq,
                                    float ms, float inv_ms,
                                    float alpha, float beta, float gamma,
                                    float& rs, float& rm, float& rl, float& tot)
{
    rs = cq - pq;
    float stop_r = (u < 0.3f) ? 0.5f : ((u > 0.7f) ? -0.5f : 0.0f);
    float cont = (u > 0.5f) ? (0.5f * u) : (-0.5f * (1.0f - u));
    cont -= (sc > 0.8f * ms) ? 0.3f : 0.0f;   // 0.8f*20.0f == 16.0f exactly, matches ref
    float t = sc * inv_ms;
    rm = ((a == 0) ? stop_r : cont) - 0.1f * t;
    rl = fq + 0.5f * (1.0f - t);
    tot = alpha * rs + beta * rm + gamma * rl;
}

__global__ __launch_bounds__(THREADS) void reward_main(
    const float* __restrict__ cq, const float* __restrict__ pq,
    const float* __restrict__ un, const int*  __restrict__ ac,
    const float* __restrict__ sc, const float* __restrict__ fq,
    const float* __restrict__ alpha_p, const float* __restrict__ beta_p,
    const float* __restrict__ gamma_p, const int* __restrict__ ms_p,
    float* __restrict__ out, double* __restrict__ partials)
{
    const float alpha = alpha_p[0], beta = beta_p[0], gamma = gamma_p[0];
    const float ms = (float)ms_p[0];
    const float inv_ms = 1.0f / ms;

    const float4* cq4 = (const float4*)cq;
    const float4* pq4 = (const float4*)pq;
    const float4* un4 = (const float4*)un;
    const int4*   ac4 = (const int4*)ac;
    const float4* sc4 = (const float4*)sc;
    const float4* fq4 = (const float4*)fq;

    double acc[NSUMS];
#pragma unroll
    for (int s = 0; s < NSUMS; ++s) acc[s] = 0.0;

    const int tid  = blockIdx.x * THREADS + threadIdx.x;   // 0 .. 524287
    const int lane = threadIdx.x & 63;

#pragma unroll
    for (int it = 0; it < ITERS; ++it) {
        const int idx4 = tid + it * (BLOCKS * THREADS);
        float4 q = cq4[idx4];
        float4 p = pq4[idx4];
        float4 u = un4[idx4];
        int4   a = ac4[idx4];
        float4 s = sc4[idx4];
        float4 f = fq4[idx4];

        float qc[4] = {q.x, q.y, q.z, q.w};
        float pc[4] = {p.x, p.y, p.z, p.w};
        float uc[4] = {u.x, u.y, u.z, u.w};
        int   av[4] = {a.x, a.y, a.z, a.w};
        float sv[4] = {s.x, s.y, s.z, s.w};
        float fv[4] = {f.x, f.y, f.z, f.w};

        float rs[4], rm[4], rl[4], tt[4];
#pragma unroll
        for (int k = 0; k < 4; ++k) {
            elem_compute(qc[k], pc[k], uc[k], av[k], sv[k], fv[k],
                         ms, inv_ms, alpha, beta, gamma,
                         rs[k], rm[k], rl[k], tt[k]);
            double ds = (double)rs[k], dm = (double)rm[k], dl = (double)rl[k];
            acc[0] += ds;      acc[1] += dm;      acc[2] += dl;
            acc[3] += ds * ds; acc[4] += dm * dm; acc[5] += dl * dl;
            acc[6] += ds * dm; acc[7] += ds * dl; acc[8] += dm * dl;
        }

        // total_reward: naturally aligned & lane-contiguous
        ((float4*)out)[idx4] = make_float4(tt[0], tt[1], tt[2], tt[3]);

        // r_short/r_mid/r_long live at +1 float offsets (N+1, 2N+1, 3N+1).
        // Re-align in registers: lane j's aligned float4 = {my v3, next-lane v0,v1,v2},
        // covering elements [b+3, b+7). Lanes 0..62 store contiguously; lanes 0/63 patch edges.
        const int b = idx4 * 4;   // element base for this lane

        float s0n = __shfl_down(rs[0], 1, 64);
        float s1n = __shfl_down(rs[1], 1, 64);
        float s2n = __shfl_down(rs[2], 1, 64);
        float m0n = __shfl_down(rm[0], 1, 64);
        float m1n = __shfl_down(rm[1], 1, 64);
        float m2n = __shfl_down(rm[2], 1, 64);
        float l0n = __shfl_down(rl[0], 1, 64);
        float l1n = __shfl_down(rl[1], 1, 64);
        float l2n = __shfl_down(rl[2], 1, 64);

        if (lane < 63) {
            *(float4*)(out +     N + 4 + b) = make_float4(rs[3], s0n, s1n, s2n);
            *(float4*)(out + 2 * N + 4 + b) = make_float4(rm[3], m0n, m1n, m2n);
            *(float4*)(out + 3 * N + 4 + b) = make_float4(rl[3], l0n, l1n, l2n);
        }
        if (lane == 0) {
            out[    N + 1 + b] = rs[0]; out[    N + 2 + b] = rs[1]; out[    N + 3 + b] = rs[2];
            out[2 * N + 1 + b] = rm[0]; out[2 * N + 2 + b] = rm[1]; out[2 * N + 3 + b] = rm[2];
            out[3 * N + 1 + b] = rl[0]; out[3 * N + 2 + b] = rl[1]; out[3 * N + 3 + b] = rl[2];
        }
        if (lane == 63) {
            out[    N + 4 + b] = rs[3];   // element b+3 at float index N+1+(b+3)
            out[2 * N + 4 + b] = rm[3];
            out[3 * N + 4 + b] = rl[3];
        }
    }

    // block reduction of 9 sums
    __shared__ double red[NSUMS][THREADS / 64];
    const int wave = threadIdx.x >> 6;
#pragma unroll
    for (int s = 0; s < NSUMS; ++s) {
        double w = wave_reduce(acc[s]);
        if (lane == 0) red[s][wave] = w;
    }
    __syncthreads();
    if (threadIdx.x == 0) {
#pragma unroll
        for (int s = 0; s < NSUMS; ++s) {
            double t = 0.0;
#pragma unroll
            for (int w = 0; w < THREADS / 64; ++w) t += red[s][w];
            partials[blockIdx.x * NSUMS + s] = t;
        }
    }
}

__global__ __launch_bounds__(256) void reward_finish(const double* __restrict__ partials,
                                                     float* __restrict__ out)
{
    double loc[NSUMS];
#pragma unroll
    for (int s = 0; s < NSUMS; ++s) loc[s] = 0.0;
    for (int i = threadIdx.x; i < BLOCKS; i += 256) {
#pragma unroll
        for (int s = 0; s < NSUMS; ++s) loc[s] += partials[i * NSUMS + s];
    }
    __shared__ double red[NSUMS][4];
    const int lane = threadIdx.x & 63;
    const int wave = threadIdx.x >> 6;
#pragma unroll
    for (int s = 0; s < NSUMS; ++s) {
        double w = wave_reduce(loc[s]);
        if (lane == 0) red[s][wave] = w;
    }
    __syncthreads();
    if (threadIdx.x == 0) {
        double S[NSUMS];
#pragma unroll
        for (int s = 0; s < NSUMS; ++s)
            S[s] = red[s][0] + red[s][1] + red[s][2] + red[s][3];

        const double n = (double)N;
        double mx = S[0] / n, mm = S[1] / n, ml = S[2] / n;
        double cov_sm = S[6] / n - mx * mm;
        double cov_sl = S[7] / n - mx * ml;
        double cov_ml = S[8] / n - mm * ml;
        double sdS = sqrt((S[3] - n * mx * mx) / (n - 1.0)) + 1e-8;
        double sdM = sqrt((S[4] - n * mm * mm) / (n - 1.0)) + 1e-8;
        double sdL = sqrt((S[5] - n * ml * ml) / (n - 1.0)) + 1e-8;
        double c1 = cov_sm / (sdS * sdM);
        double c2 = cov_sl / (sdS * sdL);
        double c3 = cov_ml / (sdM * sdL);
        out[N] = (float)(c1 * c1 + c2 * c2 + c3 * c3);   // ORTHO_W = 1
    }
}

extern "C" void kernel_launch(void* const* d_in, const int* in_sizes, int n_in,
                              void* d_out, int out_size, void* d_ws, size_t ws_size,
                              hipStream_t stream)
{
    const float* cq   = (const float*)d_in[0];
    const float* pq   = (const float*)d_in[1];
    const float* un   = (const float*)d_in[2];
    const int*   ac   = (const int*)d_in[3];
    const float* sc   = (const float*)d_in[4];
    const float* fq   = (const float*)d_in[5];
    const float* alp  = (const float*)d_in[6];
    const float* bet  = (const float*)d_in[7];
    const float* gam  = (const float*)d_in[8];
    const int*   msp  = (const int*)d_in[9];
    float*  out      = (float*)d_out;
    double* partials = (double*)d_ws;   // 2048 * 9 * 8 B = 144 KiB

    reward_main<<<BLOCKS, THREADS, 0, stream>>>(cq, pq, un, ac, sc, fq,
                                                alp, bet, gam, msp, out, partials);
    reward_finish<<<1, 256, 0, stream>>>(partials, out);
}